// Round 1
// baseline (496.630 us; speedup 1.0000x reference)
//
#include <hip/hip_runtime.h>
#include <math.h>

// ---------------------------------------------------------------------------
// ActorNetwork forward, MI355X (gfx950).
// Shapes: B=65536, N=8, OBS0=6, OBS1=1024, OBS2=7, H=64, HC=128, NA=2.
// Strategy: bf16 MFMA (16x16x32) for all GEMMs, fp32 accum; attention
// projections algebraically hoisted (M_qk = Wq@Wk^T, Wv applied post-sum).
// Launch order: k_mqk -> k_pack -> k_env -> k_fused (stream-ordered deps).
// ---------------------------------------------------------------------------

typedef float f32x4 __attribute__((ext_vector_type(4)));
typedef __bf16 bf16x8 __attribute__((ext_vector_type(8)));
typedef unsigned short u16x8 __attribute__((ext_vector_type(8)));

#define DI __device__ __forceinline__

DI unsigned short f2bf_u(float f) {  // fp32 -> bf16 bits, RTNE
  unsigned u = __builtin_bit_cast(unsigned, f);
  u += 0x7fffu + ((u >> 16) & 1u);
  return (unsigned short)(u >> 16);
}
DI float bfu2f(unsigned short s) {  // bf16 bits -> fp32 (exact)
  unsigned u = ((unsigned)s) << 16;
  return __builtin_bit_cast(float, u);
}
DI f32x4 mfma16(u16x8 a, u16x8 b, f32x4 c) {
  return __builtin_amdgcn_mfma_f32_16x16x32_bf16(
      __builtin_bit_cast(bf16x8, a), __builtin_bit_cast(bf16x8, b), c, 0, 0, 0);
}

// Fragment layouts (verified mappings, learn_hip m89/m91):
//   A-frag: lane l holds A[m = l&15][k = (l>>4)*8 + j], j=0..7  (8 bf16, 16B)
//   B-frag: lane l holds B[k = (l>>4)*8 + j][n = l&15]
//   C/D   : lane l holds C[row = (l>>4)*4 + ri][col = l&15], ri=0..3 (4 fp32)
// Packed frag buffers are indexed as u16x8[(kt*NT + nt)*64 + lane].

// ---- workspace layout (bytes) ----
constexpr size_t WS_ENV = 0;            // env_e bf16 [65536][64]      8388608
constexpr size_t WS_WGF = 8388608;      // Wg frags  [32kt][4nt]        131072
constexpr size_t WS_WS2 = 8519680;      // Ws2 frags [2][4]               8192
constexpr size_t WS_WV  = 8527872;      // Wv frags  [2][4]               8192
constexpr size_t WS_MQK = 8536064;      // Mqk frags [2][4]               8192
constexpr size_t WS_WC1 = 8544256;      // Wc1 frags [6][8]              49152
constexpr size_t WS_WC2 = 8593408;      // Wc2 frags [4][8]              32768
constexpr size_t WS_M32 = 8626176;      // Mqk fp32 [64][64]             16384

// ---------------------------------------------------------------------------
// kernel 0a: M_qk[i][h] = sum_d Wq[i][d] * Wk[h][d]   (fp32)
// ---------------------------------------------------------------------------
__global__ __launch_bounds__(256) void k_mqk(const float* __restrict__ Wq,
                                             const float* __restrict__ Wk,
                                             float* __restrict__ mqk) {
  const int idx = blockIdx.x * 256 + threadIdx.x;  // 4096 outputs
  const int i = idx >> 6, h = idx & 63;
  const float* qp = Wq + i * 64;
  const float* kp = Wk + h * 64;
  float acc = 0.f;
#pragma unroll 16
  for (int d = 0; d < 64; ++d) acc = fmaf(qp[d], kp[d], acc);
  mqk[idx] = acc;
}

// ---------------------------------------------------------------------------
// kernel 0b: pack weight matrices into bf16 B-fragment layout
// ---------------------------------------------------------------------------
__global__ __launch_bounds__(256) void k_pack(
    const float* __restrict__ Wg, const float* __restrict__ Ws2,
    const float* __restrict__ Wv, const float* __restrict__ mqk,
    const float* __restrict__ Wc1, const float* __restrict__ Wc2,
    unsigned short* __restrict__ wgf, unsigned short* __restrict__ ws2f,
    unsigned short* __restrict__ wvf, unsigned short* __restrict__ mqkf,
    unsigned short* __restrict__ wc1f, unsigned short* __restrict__ wc2f) {
  const int idx = blockIdx.x * 256 + threadIdx.x;  // 118784 total
  const float* src;
  unsigned short* dst;
  int i, ntm, NC;
  if (idx < 65536)      { src = Wg;  dst = wgf;  i = idx;          ntm = 2; NC = 64;  }
  else if (idx < 69632) { src = Ws2; dst = ws2f; i = idx - 65536;  ntm = 2; NC = 64;  }
  else if (idx < 73728) { src = Wv;  dst = wvf;  i = idx - 69632;  ntm = 2; NC = 64;  }
  else if (idx < 77824) { src = mqk; dst = mqkf; i = idx - 73728;  ntm = 2; NC = 64;  }
  else if (idx < 102400){ src = Wc1; dst = wc1f; i = idx - 77824;  ntm = 3; NC = 128; }
  else                  { src = Wc2; dst = wc2f; i = idx - 102400; ntm = 3; NC = 128; }
  const int j = i & 7, ln = (i >> 3) & 63, t2 = i >> 9;
  const int nt = t2 & ((1 << ntm) - 1), kt = t2 >> ntm;
  const int k = kt * 32 + (ln >> 4) * 8 + j, n = nt * 16 + (ln & 15);
  dst[i] = f2bf_u(src[k * NC + n]);
}

// ---------------------------------------------------------------------------
// kernel 1: env_e = relu(state1 @ Wg + bg) -> bf16 [B][64]
// HBM-bound: 256 MB state1 read. 4 waves/block, 16 rows/wave, K pipelined.
// ---------------------------------------------------------------------------
__global__ __launch_bounds__(256) void k_env(const float* __restrict__ s1,
                                             const float* __restrict__ bg,
                                             const unsigned short* __restrict__ wgf,
                                             unsigned short* __restrict__ env) {
  const int lane = threadIdx.x & 63, wave = threadIdx.x >> 6;
  const int lo = lane & 15, q = lane >> 4;
  const int row16 = blockIdx.x * 64 + wave * 16;
  const float* arow = s1 + (size_t)(row16 + lo) * 1024 + q * 8;
  const u16x8* wp = (const u16x8*)wgf + lane;

  f32x4 acc0 = {}, acc1 = {}, acc2 = {}, acc3 = {};
  f32x4 a0 = *(const f32x4*)(arow);
  f32x4 a1 = *(const f32x4*)(arow + 4);
  u16x8 b0 = wp[0], b1 = wp[64], b2 = wp[128], b3 = wp[192];

  for (int ks = 0; ks < 32; ++ks) {
    const f32x4 ca0 = a0, ca1 = a1;
    const u16x8 cb0 = b0, cb1 = b1, cb2 = b2, cb3 = b3;
    if (ks < 31) {  // prefetch next K-step
      const float* ap = arow + (ks + 1) * 32;
      a0 = *(const f32x4*)ap;
      a1 = *(const f32x4*)(ap + 4);
      const u16x8* bp = wp + (size_t)(ks + 1) * 256;
      b0 = bp[0]; b1 = bp[64]; b2 = bp[128]; b3 = bp[192];
    }
    u16x8 af;
    af[0] = f2bf_u(ca0[0]); af[1] = f2bf_u(ca0[1]);
    af[2] = f2bf_u(ca0[2]); af[3] = f2bf_u(ca0[3]);
    af[4] = f2bf_u(ca1[0]); af[5] = f2bf_u(ca1[1]);
    af[6] = f2bf_u(ca1[2]); af[7] = f2bf_u(ca1[3]);
    acc0 = mfma16(af, cb0, acc0);
    acc1 = mfma16(af, cb1, acc1);
    acc2 = mfma16(af, cb2, acc2);
    acc3 = mfma16(af, cb3, acc3);
  }
  const float bias[4] = {bg[lo], bg[16 + lo], bg[32 + lo], bg[48 + lo]};
  const f32x4 av[4] = {acc0, acc1, acc2, acc3};
#pragma unroll
  for (int nt = 0; nt < 4; ++nt)
#pragma unroll
    for (int ri = 0; ri < 4; ++ri) {
      float v = fmaxf(av[nt][ri] + bias[nt], 0.f);
      env[(size_t)(row16 + q * 4 + ri) * 64 + nt * 16 + lo] = f2bf_u(v);
    }
}

// ---------------------------------------------------------------------------
// kernel 2: everything else, fused. One block = 32 batch rows (256 intruder
// rows). 2048 blocks x 256 threads, 56 KB LDS (2 blocks/CU).
// ---------------------------------------------------------------------------
__global__ __launch_bounds__(256) void k_fused(
    const float* __restrict__ s0, const float* __restrict__ s2,
    const unsigned short* __restrict__ env,
    const float* __restrict__ W0, const float* __restrict__ b0v,
    const float* __restrict__ Ws1, const float* __restrict__ bs1,
    const unsigned short* __restrict__ ws2f, const float* __restrict__ bs2,
    const unsigned short* __restrict__ wvf, const unsigned short* __restrict__ mqkf,
    const unsigned short* __restrict__ wc1f, const float* __restrict__ bc1,
    const unsigned short* __restrict__ wc2f, const float* __restrict__ bc2,
    const float* __restrict__ Wc3, const float* __restrict__ bc3,
    float* __restrict__ out) {
  // LDS map (55296 B total):
  //  [0,32768)   EF   : E1 then E2 frags  [32 frag-rows][64 lanes] u16x8
  //              reused after sE2: H1F frags (8 KB) + H2 fp32 [32][132] @+8192
  //  [32768,45056) CF : concat frags [2mt][6kt][64] u16x8
  //  [45056,53248) QK : qk fp32 [32][64]; reused as sE2 frags [2mt][2kt][64]
  //  [53248,54272) SC : scores fp32 [256]
  //  [54272,55296) AL : alpha fp32 [256]
  __shared__ __align__(16) char smem[55296];
  u16x8* EF = (u16x8*)smem;
  unsigned short* EFs = (unsigned short*)smem;
  u16x8* H1F = (u16x8*)smem;
  unsigned short* H1Fs = (unsigned short*)smem;
  float* H2 = (float*)(smem + 8192);
  u16x8* CF = (u16x8*)(smem + 32768);
  unsigned short* CFs = (unsigned short*)(smem + 32768);
  float* QK = (float*)(smem + 45056);
  u16x8* SEF = (u16x8*)(smem + 45056);
  float* SC = (float*)(smem + 53248);
  float* AL = (float*)(smem + 54272);

  const int tid = threadIdx.x;
  const int lane = tid & 63, wave = tid >> 6;
  const int lo = lane & 15, q = lane >> 4;
  const int bbase = blockIdx.x * 32;

  // ---- Phase A: E1 = relu(state2 @ Ws1 + bs1) (K=7, fp32 VALU) + mask ----
  bool maskreg;
  {
    const int r = tid, bl = r >> 3, n = r & 7;
    const float* x = s2 + ((size_t)(bbase + bl) * 8 + n) * 7;
    float xv[7];
#pragma unroll
    for (int j = 0; j < 7; ++j) xv[j] = x[j];
    float sum = 0.f;
#pragma unroll
    for (int j = 0; j < 7; ++j) sum += xv[j];
    maskreg = (sum != 0.f);  // padded slots are exact zeros
    const int mt = r >> 4, rl = r & 15;
#pragma unroll
    for (int c = 0; c < 8; ++c) {  // Ws1/bs1 addrs uniform across lanes
      float a[8];
#pragma unroll
      for (int i = 0; i < 8; ++i) a[i] = bs1[c * 8 + i];
#pragma unroll
      for (int j = 0; j < 7; ++j) {
        const float* wr = Ws1 + j * 64 + c * 8;
#pragma unroll
        for (int i = 0; i < 8; ++i) a[i] = fmaf(xv[j], wr[i], a[i]);
      }
      u16x8 pk;
#pragma unroll
      for (int i = 0; i < 8; ++i) pk[i] = f2bf_u(fmaxf(a[i], 0.f));
      EF[(mt * 2 + (c >> 2)) * 64 + (((c & 3) << 4) | rl)] = pk;
    }
  }
  __syncthreads();

  // ---- Phase B: E2 = relu(E1 @ Ws2 + bs2), MFMA, in-place frag overwrite ----
  {
    u16x8 Bf[4][2];
#pragma unroll
    for (int nt = 0; nt < 4; ++nt)
#pragma unroll
      for (int kt = 0; kt < 2; ++kt)
        Bf[nt][kt] = ((const u16x8*)ws2f)[(kt * 4 + nt) * 64 + lane];
    float bias[4];
#pragma unroll
    for (int nt = 0; nt < 4; ++nt) bias[nt] = bs2[nt * 16 + lo];
#pragma unroll
    for (int mi = 0; mi < 4; ++mi) {  // wave owns mtiles wave*4..+3 only
      const int mt = wave * 4 + mi;
      const u16x8 A0 = EF[(mt * 2 + 0) * 64 + lane];
      const u16x8 A1 = EF[(mt * 2 + 1) * 64 + lane];
      f32x4 acc[4] = {};
#pragma unroll
      for (int nt = 0; nt < 4; ++nt) {
        acc[nt] = mfma16(A0, Bf[nt][0], acc[nt]);
        acc[nt] = mfma16(A1, Bf[nt][1], acc[nt]);
      }
#pragma unroll
      for (int nt = 0; nt < 4; ++nt) {
        const int h = nt * 16 + lo;
#pragma unroll
        for (int ri = 0; ri < 4; ++ri) {
          const float v = fmaxf(acc[nt][ri] + bias[nt], 0.f);
          const int rr = mt * 16 + q * 4 + ri;
          EFs[((mt * 2 + (h >> 5)) * 64 + ((((h >> 3) & 3) << 4) | (rr & 15))) * 8 +
              (h & 7)] = f2bf_u(v);
        }
      }
    }
  }
  __syncthreads();

  // ---- Phase C1: own_e (K=6 VALU) + env_e (global bf16) -> concat frags ----
  {
    const int bl = tid >> 3, c = tid & 7;
    const int mt = bl >> 4, fl = ((c & 3) << 4) | (bl & 15), kt = c >> 2;
    const float* x = s0 + (size_t)(bbase + bl) * 6;
    float xv[6];
#pragma unroll
    for (int j = 0; j < 6; ++j) xv[j] = x[j];
    float a[8];
#pragma unroll
    for (int i = 0; i < 8; ++i) a[i] = b0v[c * 8 + i];
#pragma unroll
    for (int j = 0; j < 6; ++j) {
      const float* wr = W0 + j * 64 + c * 8;
#pragma unroll
      for (int i = 0; i < 8; ++i) a[i] = fmaf(xv[j], wr[i], a[i]);
    }
    u16x8 pk;
#pragma unroll
    for (int i = 0; i < 8; ++i) pk[i] = f2bf_u(fmaxf(a[i], 0.f));
    CF[(mt * 6 + kt) * 64 + fl] = pk;  // concat kt 0,1 = own_e
    const u16x8 ev = *(const u16x8*)(env + (size_t)(bbase + bl) * 64 + c * 8);
    CF[(mt * 6 + 2 + kt) * 64 + fl] = ev;  // concat kt 2,3 = env_e
  }
  __syncthreads();

  // ---- Phase C2: qk = own_e @ M_qk (MFMA) -> QK fp32 ----
  {
#pragma unroll
    for (int pp = 0; pp < 2; ++pp) {
      const int p = wave * 2 + pp, mt = p >> 2, nt = p & 3;
      const u16x8 A0 = CF[(mt * 6 + 0) * 64 + lane];
      const u16x8 A1 = CF[(mt * 6 + 1) * 64 + lane];
      const u16x8 B0 = ((const u16x8*)mqkf)[(0 * 4 + nt) * 64 + lane];
      const u16x8 B1 = ((const u16x8*)mqkf)[(1 * 4 + nt) * 64 + lane];
      f32x4 acc = {};
      acc = mfma16(A0, B0, acc);
      acc = mfma16(A1, B1, acc);
#pragma unroll
      for (int ri = 0; ri < 4; ++ri)
        QK[(mt * 16 + q * 4 + ri) * 64 + nt * 16 + lo] = acc[ri];
    }
  }
  __syncthreads();

  // ---- Phase C3: score_r = (E2_r . qk_b)/8, masked ----
  {
    const int r = tid, bl = r >> 3, mt = r >> 4, rl = r & 15;
    float dot = 0.f;
#pragma unroll
    for (int c = 0; c < 8; ++c) {
      const u16x8 e = EF[(mt * 2 + (c >> 2)) * 64 + (((c & 3) << 4) | rl)];
      const float* qkp = QK + bl * 64 + c * 8;
      const f32x4 qa = *(const f32x4*)(qkp);
      const f32x4 qb = *(const f32x4*)(qkp + 4);
#pragma unroll
      for (int i = 0; i < 4; ++i) dot = fmaf(bfu2f(e[i]), qa[i], dot);
#pragma unroll
      for (int i = 0; i < 4; ++i) dot = fmaf(bfu2f(e[4 + i]), qb[i], dot);
    }
    SC[r] = maskreg ? dot * 0.125f : -1e30f;  // 1/sqrt(64) scale
  }
  __syncthreads();

  // ---- Phase C4: softmax over N=8 (masked lanes -> exactly 0) ----
  if (tid < 32) {
    float s[8];
#pragma unroll
    for (int n = 0; n < 8; ++n) s[n] = SC[tid * 8 + n];
    float mx = s[0];
#pragma unroll
    for (int n = 1; n < 8; ++n) mx = fmaxf(mx, s[n]);
    float e[8], sum = 0.f;
#pragma unroll
    for (int n = 0; n < 8; ++n) { e[n] = __expf(s[n] - mx); sum += e[n]; }
    const float inv = 1.f / sum;
#pragma unroll
    for (int n = 0; n < 8; ++n) AL[tid * 8 + n] = e[n] * inv;
  }
  __syncthreads();

  // ---- Phase C5: sE2_b = sum_n alpha_n * E2_{b,n} -> frags in SEF ----
  {
    const int bl = tid >> 3, c = tid & 7;
    float al[8];
#pragma unroll
    for (int n = 0; n < 8; ++n) al[n] = AL[bl * 8 + n];
    float a[8] = {0.f, 0.f, 0.f, 0.f, 0.f, 0.f, 0.f, 0.f};
#pragma unroll
    for (int n = 0; n < 8; ++n) {
      const int rr = bl * 8 + n;
      const u16x8 e =
          EF[((rr >> 4) * 2 + (c >> 2)) * 64 + (((c & 3) << 4) | (rr & 15))];
#pragma unroll
      for (int i = 0; i < 8; ++i) a[i] = fmaf(al[n], bfu2f(e[i]), a[i]);
    }
    u16x8 pk;
#pragma unroll
    for (int i = 0; i < 8; ++i) pk[i] = f2bf_u(a[i]);
    SEF[((bl >> 4) * 2 + (c >> 2)) * 64 + (((c & 3) << 4) | (bl & 15))] = pk;
  }
  __syncthreads();

  // ---- Phase C6: v_att = sE2 @ Wv (MFMA) -> concat frags kt 4,5 ----
  {
#pragma unroll
    for (int pp = 0; pp < 2; ++pp) {
      const int p = wave * 2 + pp, mt = p >> 2, nt = p & 3;
      const u16x8 A0 = SEF[(mt * 2 + 0) * 64 + lane];
      const u16x8 A1 = SEF[(mt * 2 + 1) * 64 + lane];
      const u16x8 B0 = ((const u16x8*)wvf)[(0 * 4 + nt) * 64 + lane];
      const u16x8 B1 = ((const u16x8*)wvf)[(1 * 4 + nt) * 64 + lane];
      f32x4 acc = {};
      acc = mfma16(A0, B0, acc);
      acc = mfma16(A1, B1, acc);
      const int h = nt * 16 + lo;
#pragma unroll
      for (int ri = 0; ri < 4; ++ri) {
        const int rr = mt * 16 + q * 4 + ri;
        CFs[((mt * 6 + 4 + (h >> 5)) * 64 + ((((h >> 3) & 3) << 4) | (rr & 15))) * 8 +
            (h & 7)] = f2bf_u(acc[ri]);
      }
    }
  }
  __syncthreads();

  // ---- Phase D1: h1 = relu(concat @ Wc1 + bc1), K=192 ----
  {
    const int mt = wave & 1, ntb = (wave >> 1) * 4;
    u16x8 A[6];
#pragma unroll
    for (int kt = 0; kt < 6; ++kt) A[kt] = CF[(mt * 6 + kt) * 64 + lane];
#pragma unroll
    for (int ni = 0; ni < 4; ++ni) {
      const int nt = ntb + ni;
      f32x4 acc = {};
#pragma unroll
      for (int kt = 0; kt < 6; ++kt) {
        const u16x8 Bf = ((const u16x8*)wc1f)[(kt * 8 + nt) * 64 + lane];
        acc = mfma16(A[kt], Bf, acc);
      }
      const float bias = bc1[nt * 16 + lo];
      const int h = nt * 16 + lo;
#pragma unroll
      for (int ri = 0; ri < 4; ++ri) {
        const float v = fmaxf(acc[ri] + bias, 0.f);
        const int rr = mt * 16 + q * 4 + ri;
        H1Fs[((mt * 4 + (h >> 5)) * 64 + ((((h >> 3) & 3) << 4) | (rr & 15))) * 8 +
             (h & 7)] = f2bf_u(v);
      }
    }
  }
  __syncthreads();

  // ---- Phase D2: h2 = relu(h1 @ Wc2 + bc2) -> fp32 plain [32][132] ----
  {
    const int mt = wave & 1, ntb = (wave >> 1) * 4;
    u16x8 A[4];
#pragma unroll
    for (int kt = 0; kt < 4; ++kt) A[kt] = H1F[(mt * 4 + kt) * 64 + lane];
#pragma unroll
    for (int ni = 0; ni < 4; ++ni) {
      const int nt = ntb + ni;
      f32x4 acc = {};
#pragma unroll
      for (int kt = 0; kt < 4; ++kt) {
        const u16x8 Bf = ((const u16x8*)wc2f)[(kt * 8 + nt) * 64 + lane];
        acc = mfma16(A[kt], Bf, acc);
      }
      const float bias = bc2[nt * 16 + lo];
#pragma unroll
      for (int ri = 0; ri < 4; ++ri)
        H2[(mt * 16 + q * 4 + ri) * 132 + nt * 16 + lo] =
            fmaxf(acc[ri] + bias, 0.f);
    }
  }
  __syncthreads();

  // ---- Phase D3: out = tanh(h2 @ Wc3 + bc3), fp32 (no final bf16 round) ----
  if (tid < 64) {
    const int bl = tid >> 1, a = tid & 1;
    float acc = bc3[a];
    const float* h2r = H2 + bl * 132;
#pragma unroll 8
    for (int h = 0; h < 128; ++h) acc = fmaf(h2r[h], Wc3[h * 2 + a], acc);
    out[(size_t)(bbase + bl) * 2 + a] = tanhf(acc);
  }
}

// ---------------------------------------------------------------------------
extern "C" void kernel_launch(void* const* d_in, const int* in_sizes, int n_in,
                              void* d_out, int out_size, void* d_ws, size_t ws_size,
                              hipStream_t stream) {
  const float* s0  = (const float*)d_in[0];
  const float* s1  = (const float*)d_in[1];
  const float* s2  = (const float*)d_in[2];
  const float* W0  = (const float*)d_in[3];
  const float* b0  = (const float*)d_in[4];
  const float* Wg  = (const float*)d_in[5];
  const float* bg  = (const float*)d_in[6];
  const float* Ws1 = (const float*)d_in[7];
  const float* bs1 = (const float*)d_in[8];
  const float* Ws2 = (const float*)d_in[9];
  const float* bs2 = (const float*)d_in[10];
  const float* Wq  = (const float*)d_in[11];
  const float* Wk  = (const float*)d_in[12];
  const float* Wv  = (const float*)d_in[13];
  const float* Wc1 = (const float*)d_in[14];
  const float* bc1 = (const float*)d_in[15];
  const float* Wc2 = (const float*)d_in[16];
  const float* bc2 = (const float*)d_in[17];
  const float* Wc3 = (const float*)d_in[18];
  const float* bc3 = (const float*)d_in[19];

  char* ws = (char*)d_ws;
  unsigned short* env  = (unsigned short*)(ws + WS_ENV);
  unsigned short* wgf  = (unsigned short*)(ws + WS_WGF);
  unsigned short* ws2f = (unsigned short*)(ws + WS_WS2);
  unsigned short* wvf  = (unsigned short*)(ws + WS_WV);
  unsigned short* mqkf = (unsigned short*)(ws + WS_MQK);
  unsigned short* wc1f = (unsigned short*)(ws + WS_WC1);
  unsigned short* wc2f = (unsigned short*)(ws + WS_WC2);
  float* mqk32 = (float*)(ws + WS_M32);

  hipLaunchKernelGGL(k_mqk, dim3(16), dim3(256), 0, stream, Wq, Wk, mqk32);
  hipLaunchKernelGGL(k_pack, dim3(464), dim3(256), 0, stream, Wg, Ws2, Wv, mqk32,
                     Wc1, Wc2, wgf, ws2f, wvf, mqkf, wc1f, wc2f);
  hipLaunchKernelGGL(k_env, dim3(1024), dim3(256), 0, stream, s1, bg, wgf, env);
  hipLaunchKernelGGL(k_fused, dim3(2048), dim3(256), 0, stream, s0, s2, env, W0,
                     b0, Ws1, bs1, ws2f, bs2, wvf, mqkf, wc1f, bc1, wc2f, bc2,
                     Wc3, bc3, (float*)d_out);
}

// Round 2
// 460.215 us; speedup vs baseline: 1.0791x; 1.0791x over previous
//
#include <hip/hip_runtime.h>
#include <math.h>

// ---------------------------------------------------------------------------
// ActorNetwork forward, MI355X (gfx950). Round 2: single fused main kernel.
// Shapes: B=65536, N=8, OBS0=6, OBS1=1024, OBS2=7, H=64, HC=128, NA=2.
// k_prep packs all weights to bf16 MFMA B-frags (M_qk = Wq@Wk^T computed
// inline). k_main: 2048 blocks x 32 batch rows; env GEMM (split-K x2 over
// waves) -> LDS concat frags -> E1/E2 -> attention -> MLP head, no global
// intermediate round-trips. LDS 54272 B -> 3 blocks/CU.
// ---------------------------------------------------------------------------

typedef float f32x4 __attribute__((ext_vector_type(4)));
typedef float f32x4u __attribute__((ext_vector_type(4), aligned(4)));
typedef float f32x2u __attribute__((ext_vector_type(2), aligned(4)));
typedef __bf16 bf16x8 __attribute__((ext_vector_type(8)));
typedef unsigned short u16x8 __attribute__((ext_vector_type(8)));

#define DI __device__ __forceinline__

DI unsigned short f2bf_u(float f) {  // fp32 -> bf16 bits, RTNE (epilogues)
  unsigned u = __builtin_bit_cast(unsigned, f);
  u += 0x7fffu + ((u >> 16) & 1u);
  return (unsigned short)(u >> 16);
}
DI float bfu2f(unsigned short s) {
  unsigned u = ((unsigned)s) << 16;
  return __builtin_bit_cast(float, u);
}
DI u16x8 cvt8(f32x4 x, f32x4 y) {  // native cvt (v_cvt_pk_bf16_f32 on gfx950)
  bf16x8 r;
  r[0] = (__bf16)x[0]; r[1] = (__bf16)x[1]; r[2] = (__bf16)x[2]; r[3] = (__bf16)x[3];
  r[4] = (__bf16)y[0]; r[5] = (__bf16)y[1]; r[6] = (__bf16)y[2]; r[7] = (__bf16)y[3];
  return __builtin_bit_cast(u16x8, r);
}
DI f32x4 mfma16(u16x8 a, u16x8 b, f32x4 c) {
  return __builtin_amdgcn_mfma_f32_16x16x32_bf16(
      __builtin_bit_cast(bf16x8, a), __builtin_bit_cast(bf16x8, b), c, 0, 0, 0);
}

// Fragment layouts (learn_hip m89/m91):
//   A-frag: lane l holds A[m = l&15][k = (l>>4)*8 + j], j=0..7
//   B-frag: lane l holds B[k = (l>>4)*8 + j][n = l&15]
//   C/D   : lane l holds C[row = (l>>4)*4 + ri][col = l&15]
// Packed frag buffers: u16x8[(kt*NT + nt)*64 + lane].

// ---- workspace layout (bytes) ----
constexpr size_t WS_WGF = 0;        // Wg frags  [32kt][4nt]   131072
constexpr size_t WS_WS2 = 131072;   // Ws2 frags [2][4]          8192
constexpr size_t WS_WV  = 139264;   // Wv frags  [2][4]          8192
constexpr size_t WS_MQK = 147456;   // Mqk frags [2][4]          8192
constexpr size_t WS_WC1 = 155648;   // Wc1 frags [6][8]         49152
constexpr size_t WS_WC2 = 204800;   // Wc2 frags [4][8]         32768

// ---------------------------------------------------------------------------
// k_prep: pack all weights into bf16 B-frag layout; M_qk computed inline.
// ---------------------------------------------------------------------------
__global__ __launch_bounds__(256) void k_prep(
    const float* __restrict__ Wg, const float* __restrict__ Ws2,
    const float* __restrict__ Wv, const float* __restrict__ Wq,
    const float* __restrict__ Wk, const float* __restrict__ Wc1,
    const float* __restrict__ Wc2,
    unsigned short* __restrict__ wgf, unsigned short* __restrict__ ws2f,
    unsigned short* __restrict__ wvf, unsigned short* __restrict__ mqkf,
    unsigned short* __restrict__ wc1f, unsigned short* __restrict__ wc2f) {
  const int idx = blockIdx.x * 256 + threadIdx.x;  // 118784 total
  const float* src = nullptr;
  unsigned short* dst;
  int i, ntm, NC;
  bool is_mqk = false;
  if (idx < 65536)      { src = Wg;  dst = wgf;  i = idx;          ntm = 2; NC = 64;  }
  else if (idx < 69632) { src = Ws2; dst = ws2f; i = idx - 65536;  ntm = 2; NC = 64;  }
  else if (idx < 73728) { src = Wv;  dst = wvf;  i = idx - 69632;  ntm = 2; NC = 64;  }
  else if (idx < 77824) { is_mqk = true; dst = mqkf; i = idx - 73728; ntm = 2; NC = 64; }
  else if (idx < 102400){ src = Wc1; dst = wc1f; i = idx - 77824;  ntm = 3; NC = 128; }
  else                  { src = Wc2; dst = wc2f; i = idx - 102400; ntm = 3; NC = 128; }
  const int j = i & 7, ln = (i >> 3) & 63, t2 = i >> 9;
  const int nt = t2 & ((1 << ntm) - 1), kt = t2 >> ntm;
  const int k = kt * 32 + (ln >> 4) * 8 + j, n = nt * 16 + (ln & 15);
  float val;
  if (is_mqk) {  // M_qk[k][n] = dot(Wq[k,:], Wk[n,:])
    const f32x4* qp = (const f32x4*)(Wq + k * 64);
    const f32x4* kp = (const f32x4*)(Wk + n * 64);
    float acc = 0.f;
#pragma unroll
    for (int d4 = 0; d4 < 16; ++d4) {
      const f32x4 a = qp[d4], b = kp[d4];
#pragma unroll
      for (int e = 0; e < 4; ++e) acc = fmaf(a[e], b[e], acc);
    }
    val = acc;
  } else {
    val = src[k * NC + n];
  }
  dst[i] = f2bf_u(val);
}

// ---------------------------------------------------------------------------
// k_main: whole network for 32 batch rows per block. 2048 blocks x 256 thr.
// ---------------------------------------------------------------------------
__global__ __launch_bounds__(256, 3) void k_main(
    const float* __restrict__ s0, const float* __restrict__ s1,
    const float* __restrict__ s2,
    const float* __restrict__ W0, const float* __restrict__ b0v,
    const float* __restrict__ bg,
    const float* __restrict__ Ws1, const float* __restrict__ bs1,
    const unsigned short* __restrict__ ws2f, const float* __restrict__ bs2,
    const unsigned short* __restrict__ wvf, const unsigned short* __restrict__ mqkf,
    const unsigned short* __restrict__ wc1f, const float* __restrict__ bc1,
    const unsigned short* __restrict__ wc2f, const float* __restrict__ bc2,
    const float* __restrict__ Wc3, const float* __restrict__ bc3,
    const unsigned short* __restrict__ wgf,
    float* __restrict__ out) {
  // LDS map (54272 B -> 3 blocks/CU):
  //  [0,32768)     EF  : E1/E2 frags [16mt][2kt][64] u16x8
  //                later: H1F frags [2][4][64] (8 KB) + H2 fp32 [32][132] @+8192
  //  [32768,45056) CF  : concat frags [2mt][6kt][64] (kt 0,1 own; 2,3 env; 4,5 vatt)
  //  [45056,53248) QK  : env split-K partials f32x4 [4nt][128]; qk fp32 [32][64];
  //                      sE2 frags [2][2][64]
  //  [53248,54272) SC  : scores -> alpha fp32 [256] (softmax in place)
  __shared__ __align__(16) char smem[54272];
  u16x8* EF = (u16x8*)smem;
  unsigned short* EFs = (unsigned short*)smem;
  u16x8* H1F = (u16x8*)smem;
  unsigned short* H1Fs = (unsigned short*)smem;
  float* H2 = (float*)(smem + 8192);
  u16x8* CF = (u16x8*)(smem + 32768);
  unsigned short* CFs = (unsigned short*)(smem + 32768);
  float* QK = (float*)(smem + 45056);
  f32x4* RED4 = (f32x4*)(smem + 45056);
  u16x8* SEF = (u16x8*)(smem + 45056);
  float* SC = (float*)(smem + 53248);

  const int tid = threadIdx.x;
  const int lane = tid & 63, wave = tid >> 6;
  const int lo = lane & 15, q = lane >> 4;
  const int bbase = blockIdx.x * 32;

  // ---- early global loads for phases A / C1 (latency hidden under env) ----
  const int bl8 = tid >> 3, n8 = tid & 7;
  const float* s2p = s2 + ((size_t)(bbase + bl8) * 8 + n8) * 7;
  const f32x4u x03 = *(const f32x4u*)s2p;
  const f32x2u x45 = *(const f32x2u*)(s2p + 4);
  const float x6 = s2p[6];
  const float* s0p = s0 + (size_t)(bbase + bl8) * 6;
  const f32x4u y03 = *(const f32x4u*)s0p;
  const f32x2u y45 = *(const f32x2u*)(s0p + 4);

  // ---- env GEMM: wave handles rows emt*16..+15, K-half p (512 each) ----
  const int p = wave & 1, emt = wave >> 1;
  {
    const float* arow =
        s1 + (size_t)(bbase + emt * 16 + lo) * 1024 + p * 512 + q * 8;
    const u16x8* wp = (const u16x8*)wgf + p * 4096 + lane;
    f32x4 acc0 = {}, acc1 = {}, acc2 = {}, acc3 = {};
    f32x4 a0 = *(const f32x4*)arow, a1 = *(const f32x4*)(arow + 4);
    u16x8 b0 = wp[0], b1 = wp[64], b2 = wp[128], b3 = wp[192];
    for (int ks = 0; ks < 16; ++ks) {
      const f32x4 ca0 = a0, ca1 = a1;
      const u16x8 cb0 = b0, cb1 = b1, cb2 = b2, cb3 = b3;
      if (ks < 15) {  // software pipeline: prefetch next K-step
        const float* ap = arow + (ks + 1) * 32;
        a0 = *(const f32x4*)ap;
        a1 = *(const f32x4*)(ap + 4);
        const u16x8* bp = wp + (ks + 1) * 256;
        b0 = bp[0]; b1 = bp[64]; b2 = bp[128]; b3 = bp[192];
      }
      const u16x8 af = cvt8(ca0, ca1);
      acc0 = mfma16(af, cb0, acc0);
      acc1 = mfma16(af, cb1, acc1);
      acc2 = mfma16(af, cb2, acc2);
      acc3 = mfma16(af, cb3, acc3);
    }
    if (p) {  // write partials for reduction
      RED4[0 * 128 + emt * 64 + lane] = acc0;
      RED4[1 * 128 + emt * 64 + lane] = acc1;
      RED4[2 * 128 + emt * 64 + lane] = acc2;
      RED4[3 * 128 + emt * 64 + lane] = acc3;
    }
    __syncthreads();
    if (!p) {  // reduce + bias + relu -> concat frags kt 2,3 (env_e)
      acc0 += RED4[0 * 128 + emt * 64 + lane];
      acc1 += RED4[1 * 128 + emt * 64 + lane];
      acc2 += RED4[2 * 128 + emt * 64 + lane];
      acc3 += RED4[3 * 128 + emt * 64 + lane];
      const f32x4 av[4] = {acc0, acc1, acc2, acc3};
#pragma unroll
      for (int nt = 0; nt < 4; ++nt) {
        const float bias = bg[nt * 16 + lo];
        const int h = nt * 16 + lo;
#pragma unroll
        for (int ri = 0; ri < 4; ++ri) {
          const float v = fmaxf(av[nt][ri] + bias, 0.f);
          CFs[((emt * 6 + 2 + (h >> 5)) * 64 +
               ((((h >> 3) & 3) << 4) | (q * 4 + ri))) * 8 + (h & 7)] = f2bf_u(v);
        }
      }
    }
  }
  // (no barrier: phase A touches only EF; CF env-writes fenced before D1)

  // ---- Phase A: E1 = relu(state2 @ Ws1 + bs1), K=7 fp32 VALU; mask ----
  bool maskreg;
  {
    float xv[7] = {x03[0], x03[1], x03[2], x03[3], x45[0], x45[1], x6};
    const float sum = xv[0] + xv[1] + xv[2] + xv[3] + xv[4] + xv[5] + xv[6];
    maskreg = (sum != 0.f);  // padded slots are exact zeros
    const int mt = tid >> 4, rl = tid & 15;
#pragma unroll
    for (int c = 0; c < 8; ++c) {
      float a[8];
#pragma unroll
      for (int i = 0; i < 8; ++i) a[i] = bs1[c * 8 + i];
#pragma unroll
      for (int j = 0; j < 7; ++j) {
        const float* wr = Ws1 + j * 64 + c * 8;
#pragma unroll
        for (int i = 0; i < 8; ++i) a[i] = fmaf(xv[j], wr[i], a[i]);
      }
      u16x8 pk;
#pragma unroll
      for (int i = 0; i < 8; ++i) pk[i] = f2bf_u(fmaxf(a[i], 0.f));
      EF[(mt * 2 + (c >> 2)) * 64 + (((c & 3) << 4) | rl)] = pk;
    }
  }
  __syncthreads();

  // ---- Phase B: E2 = relu(E1 @ Ws2 + bs2), MFMA, in-place frag overwrite ----
  {
    u16x8 Bf[4][2];
#pragma unroll
    for (int nt = 0; nt < 4; ++nt)
#pragma unroll
      for (int kt = 0; kt < 2; ++kt)
        Bf[nt][kt] = ((const u16x8*)ws2f)[(kt * 4 + nt) * 64 + lane];
    float bias[4];
#pragma unroll
    for (int nt = 0; nt < 4; ++nt) bias[nt] = bs2[nt * 16 + lo];
#pragma unroll
    for (int mi = 0; mi < 4; ++mi) {  // wave owns mtiles wave*4..+3
      const int mt = wave * 4 + mi;
      const u16x8 A0 = EF[(mt * 2 + 0) * 64 + lane];
      const u16x8 A1 = EF[(mt * 2 + 1) * 64 + lane];
      f32x4 acc[4] = {};
#pragma unroll
      for (int nt = 0; nt < 4; ++nt) {
        acc[nt] = mfma16(A0, Bf[nt][0], acc[nt]);
        acc[nt] = mfma16(A1, Bf[nt][1], acc[nt]);
      }
#pragma unroll
      for (int nt = 0; nt < 4; ++nt) {
        const int h = nt * 16 + lo;
#pragma unroll
        for (int ri = 0; ri < 4; ++ri) {
          const float v = fmaxf(acc[nt][ri] + bias[nt], 0.f);
          const int rr = mt * 16 + q * 4 + ri;
          EFs[((mt * 2 + (h >> 5)) * 64 + ((((h >> 3) & 3) << 4) | (rr & 15))) * 8 +
              (h & 7)] = f2bf_u(v);
        }
      }
    }
  }
  __syncthreads();

  // ---- Phase C1: own_e = relu(s0 @ W0 + b0), K=6 VALU -> concat kt 0,1 ----
  {
    const int mt = bl8 >> 4, fl = ((n8 & 3) << 4) | (bl8 & 15), kt = n8 >> 2;
    const float yv[6] = {y03[0], y03[1], y03[2], y03[3], y45[0], y45[1]};
    float a[8];
#pragma unroll
    for (int i = 0; i < 8; ++i) a[i] = b0v[n8 * 8 + i];
#pragma unroll
    for (int j = 0; j < 6; ++j) {
      const float* wr = W0 + j * 64 + n8 * 8;
#pragma unroll
      for (int i = 0; i < 8; ++i) a[i] = fmaf(yv[j], wr[i], a[i]);
    }
    u16x8 pk;
#pragma unroll
    for (int i = 0; i < 8; ++i) pk[i] = f2bf_u(fmaxf(a[i], 0.f));
    CF[(mt * 6 + kt) * 64 + fl] = pk;
  }
  __syncthreads();

  // ---- Phase C2: qk = own_e @ M_qk (MFMA) -> QK fp32 [32][64] ----
  {
#pragma unroll
    for (int pp = 0; pp < 2; ++pp) {
      const int pr = wave * 2 + pp, mt = pr >> 2, nt = pr & 3;
      const u16x8 A0 = CF[(mt * 6 + 0) * 64 + lane];
      const u16x8 A1 = CF[(mt * 6 + 1) * 64 + lane];
      const u16x8 B0 = ((const u16x8*)mqkf)[(0 * 4 + nt) * 64 + lane];
      const u16x8 B1 = ((const u16x8*)mqkf)[(1 * 4 + nt) * 64 + lane];
      f32x4 acc = {};
      acc = mfma16(A0, B0, acc);
      acc = mfma16(A1, B1, acc);
#pragma unroll
      for (int ri = 0; ri < 4; ++ri)
        QK[(mt * 16 + q * 4 + ri) * 64 + nt * 16 + lo] = acc[ri];
    }
  }
  __syncthreads();

  // ---- Phase C3: score_r = (E2_r . qk_b)/8, masked -> SC ----
  {
    const int r = tid, bl = r >> 3, mt = r >> 4, rl = r & 15;
    float dot = 0.f;
#pragma unroll
    for (int c = 0; c < 8; ++c) {
      const u16x8 e = EF[(mt * 2 + (c >> 2)) * 64 + (((c & 3) << 4) | rl)];
      const float* qkp = QK + bl * 64 + c * 8;
      const f32x4 qa = *(const f32x4*)(qkp);
      const f32x4 qb = *(const f32x4*)(qkp + 4);
#pragma unroll
      for (int i = 0; i < 4; ++i) dot = fmaf(bfu2f(e[i]), qa[i], dot);
#pragma unroll
      for (int i = 0; i < 4; ++i) dot = fmaf(bfu2f(e[4 + i]), qb[i], dot);
    }
    SC[r] = maskreg ? dot * 0.125f : -1e30f;  // 1/sqrt(64)
  }
  __syncthreads();

  // ---- Phase C4: softmax over N=8, in place in SC ----
  if (tid < 32) {
    float s[8];
#pragma unroll
    for (int n = 0; n < 8; ++n) s[n] = SC[tid * 8 + n];
    float mx = s[0];
#pragma unroll
    for (int n = 1; n < 8; ++n) mx = fmaxf(mx, s[n]);
    float e[8], sum = 0.f;
#pragma unroll
    for (int n = 0; n < 8; ++n) { e[n] = __expf(s[n] - mx); sum += e[n]; }
    const float inv = 1.f / sum;
#pragma unroll
    for (int n = 0; n < 8; ++n) SC[tid * 8 + n] = e[n] * inv;
  }
  __syncthreads();

  // ---- Phase C5: sE2_b = sum_n alpha_n * E2_{b,n} -> SEF frags ----
  {
    float al[8];
#pragma unroll
    for (int n = 0; n < 8; ++n) al[n] = SC[bl8 * 8 + n];
    float a[8] = {0.f, 0.f, 0.f, 0.f, 0.f, 0.f, 0.f, 0.f};
#pragma unroll
    for (int n = 0; n < 8; ++n) {
      const int rr = bl8 * 8 + n;
      const u16x8 e =
          EF[((rr >> 4) * 2 + (n8 >> 2)) * 64 + (((n8 & 3) << 4) | (rr & 15))];
#pragma unroll
      for (int i = 0; i < 8; ++i) a[i] = fmaf(al[n], bfu2f(e[i]), a[i]);
    }
    u16x8 pk;
#pragma unroll
    for (int i = 0; i < 8; ++i) pk[i] = f2bf_u(a[i]);
    SEF[((bl8 >> 4) * 2 + (n8 >> 2)) * 64 + (((n8 & 3) << 4) | (bl8 & 15))] = pk;
  }
  __syncthreads();

  // ---- Phase C6: v_att = sE2 @ Wv (MFMA) -> concat frags kt 4,5 ----
  {
#pragma unroll
    for (int pp = 0; pp < 2; ++pp) {
      const int pr = wave * 2 + pp, mt = pr >> 2, nt = pr & 3;
      const u16x8 A0 = SEF[(mt * 2 + 0) * 64 + lane];
      const u16x8 A1 = SEF[(mt * 2 + 1) * 64 + lane];
      const u16x8 B0 = ((const u16x8*)wvf)[(0 * 4 + nt) * 64 + lane];
      const u16x8 B1 = ((const u16x8*)wvf)[(1 * 4 + nt) * 64 + lane];
      f32x4 acc = {};
      acc = mfma16(A0, B0, acc);
      acc = mfma16(A1, B1, acc);
      const int h = nt * 16 + lo;
#pragma unroll
      for (int ri = 0; ri < 4; ++ri) {
        const int rr = mt * 16 + q * 4 + ri;
        CFs[((mt * 6 + 4 + (h >> 5)) * 64 + ((((h >> 3) & 3) << 4) | (rr & 15))) * 8 +
            (h & 7)] = f2bf_u(acc[ri]);
      }
    }
  }
  __syncthreads();

  // ---- Phase D1: h1 = relu(concat @ Wc1 + bc1), K=192 -> H1F frags ----
  {
    const int mt = wave & 1, ntb = (wave >> 1) * 4;
    u16x8 A[6];
#pragma unroll
    for (int kt = 0; kt < 6; ++kt) A[kt] = CF[(mt * 6 + kt) * 64 + lane];
#pragma unroll
    for (int ni = 0; ni < 4; ++ni) {
      const int nt = ntb + ni;
      f32x4 acc = {};
#pragma unroll
      for (int kt = 0; kt < 6; ++kt) {
        const u16x8 Bf = ((const u16x8*)wc1f)[(kt * 8 + nt) * 64 + lane];
        acc = mfma16(A[kt], Bf, acc);
      }
      const float bias = bc1[nt * 16 + lo];
      const int h = nt * 16 + lo;
#pragma unroll
      for (int ri = 0; ri < 4; ++ri) {
        const float v = fmaxf(acc[ri] + bias, 0.f);
        const int rr = mt * 16 + q * 4 + ri;
        H1Fs[((mt * 4 + (h >> 5)) * 64 + ((((h >> 3) & 3) << 4) | (rr & 15))) * 8 +
             (h & 7)] = f2bf_u(v);
      }
    }
  }
  __syncthreads();

  // ---- Phase D2: h2 = relu(h1 @ Wc2 + bc2) -> H2 fp32 [32][132] ----
  {
    const int mt = wave & 1, ntb = (wave >> 1) * 4;
    u16x8 A[4];
#pragma unroll
    for (int kt = 0; kt < 4; ++kt) A[kt] = H1F[(mt * 4 + kt) * 64 + lane];
#pragma unroll
    for (int ni = 0; ni < 4; ++ni) {
      const int nt = ntb + ni;
      f32x4 acc = {};
#pragma unroll
      for (int kt = 0; kt < 4; ++kt) {
        const u16x8 Bf = ((const u16x8*)wc2f)[(kt * 8 + nt) * 64 + lane];
        acc = mfma16(A[kt], Bf, acc);
      }
      const float bias = bc2[nt * 16 + lo];
#pragma unroll
      for (int ri = 0; ri < 4; ++ri)
        H2[(mt * 16 + q * 4 + ri) * 132 + nt * 16 + lo] =
            fmaxf(acc[ri] + bias, 0.f);
    }
  }
  __syncthreads();

  // ---- Phase D3: out = tanh(h2 @ Wc3 + bc3), fp32, all 256 threads ----
  {
    const int kq = n8 >> 1, a = n8 & 1;  // 4 K-quarters x 2 actions per row
    const f32x4* h4 = (const f32x4*)(H2 + bl8 * 132 + kq * 32);
    const float* wr = Wc3 + kq * 64;  // Wc3[h][2], h = kq*32 + j
    float acc = 0.f;
#pragma unroll
    for (int j4 = 0; j4 < 8; ++j4) {
      const f32x4 hv = h4[j4];
#pragma unroll
      for (int e = 0; e < 4; ++e) acc = fmaf(hv[e], wr[(j4 * 4 + e) * 2 + a], acc);
    }
    acc += __shfl_down(acc, 2);
    acc += __shfl_down(acc, 4);
    if (kq == 0) out[(size_t)(bbase + bl8) * 2 + a] = tanhf(acc + bc3[a]);
  }
}

// ---------------------------------------------------------------------------
extern "C" void kernel_launch(void* const* d_in, const int* in_sizes, int n_in,
                              void* d_out, int out_size, void* d_ws, size_t ws_size,
                              hipStream_t stream) {
  const float* s0  = (const float*)d_in[0];
  const float* s1  = (const float*)d_in[1];
  const float* s2  = (const float*)d_in[2];
  const float* W0  = (const float*)d_in[3];
  const float* b0  = (const float*)d_in[4];
  const float* Wg  = (const float*)d_in[5];
  const float* bg  = (const float*)d_in[6];
  const float* Ws1 = (const float*)d_in[7];
  const float* bs1 = (const float*)d_in[8];
  const float* Ws2 = (const float*)d_in[9];
  const float* bs2 = (const float*)d_in[10];
  const float* Wq  = (const float*)d_in[11];
  const float* Wk  = (const float*)d_in[12];
  const float* Wv  = (const float*)d_in[13];
  const float* Wc1 = (const float*)d_in[14];
  const float* bc1 = (const float*)d_in[15];
  const float* Wc2 = (const float*)d_in[16];
  const float* bc2 = (const float*)d_in[17];
  const float* Wc3 = (const float*)d_in[18];
  const float* bc3 = (const float*)d_in[19];

  char* ws = (char*)d_ws;
  unsigned short* wgf  = (unsigned short*)(ws + WS_WGF);
  unsigned short* ws2f = (unsigned short*)(ws + WS_WS2);
  unsigned short* wvf  = (unsigned short*)(ws + WS_WV);
  unsigned short* mqkf = (unsigned short*)(ws + WS_MQK);
  unsigned short* wc1f = (unsigned short*)(ws + WS_WC1);
  unsigned short* wc2f = (unsigned short*)(ws + WS_WC2);

  hipLaunchKernelGGL(k_prep, dim3(464), dim3(256), 0, stream, Wg, Ws2, Wv, Wq,
                     Wk, Wc1, Wc2, wgf, ws2f, wvf, mqkf, wc1f, wc2f);
  hipLaunchKernelGGL(k_main, dim3(2048), dim3(256), 0, stream, s0, s1, s2, W0,
                     b0, bg, Ws1, bs1, ws2f, bs2, wvf, mqkf, wc1f, bc1, wc2f,
                     bc2, Wc3, bc3, wgf, (float*)d_out);
}